// Round 12
// baseline (3934.153 us; speedup 1.0000x reference)
//
#include <hip/hip_runtime.h>
#include <cstdint>
#include <cstddef>

typedef short short8 __attribute__((ext_vector_type(8)));
typedef float f32x4 __attribute__((ext_vector_type(4)));
typedef int   i32x4 __attribute__((ext_vector_type(4)));

#define NPATCH 262144
#define NBAGS  32
#define IN_DIM 1024
#define F_DIM  256
#define A_DIM  128
#define ROWSB  128
#define NBLK   (NPATCH / ROWSB)    // 2048

__device__ __forceinline__ unsigned short f2bf(float f){
  uint32_t u = __builtin_bit_cast(uint32_t, f);
  u += 0x7fffu + ((u >> 16) & 1u);
  return (unsigned short)(u >> 16);
}
__device__ __forceinline__ float bf2f(unsigned short h){
  return __builtin_bit_cast(float, (uint32_t)h << 16);
}
__device__ __forceinline__ float tanh_fast(float x){
  float e = __expf(2.f * x);
  return (e - 1.f) * __builtin_amdgcn_rcpf(e + 1.f);
}
__device__ __forceinline__ uint32_t cvtpk(float a, float b){
  uint32_t r;
  asm("v_cvt_pk_bf16_f32 %0, %1, %2" : "=v"(r) : "v"(a), "v"(b));
  return r;
}
__device__ __forceinline__ void gload_lds16(const void* g, void* l){
  __builtin_amdgcn_global_load_lds((const __attribute__((address_space(1))) void*)g,
                                   (__attribute__((address_space(3))) void*)l, 16, 0, 0);
}

#define MFMA(a,b,c) __builtin_amdgcn_mfma_f32_16x16x32_bf16((a),(b),(c),0,0,0)
#define SWZ4(r)  (((r) & 3) << 4)
#define SWZH(r)  (((r) & 7) << 4)

// ---------- prep: W1, Wa1 -> bf16 in ws; zero bag accumulators ----------
__global__ void prep_kernel(const float* __restrict__ W1, const float* __restrict__ Wa1,
                            unsigned short* __restrict__ w1b, unsigned short* __restrict__ wa1b,
                            float* __restrict__ bagAcc){
  int id = blockIdx.x * 256 + threadIdx.x;
  if (id < F_DIM*IN_DIM) {
    w1b[id] = f2bf(W1[id]);
  } else if (id < F_DIM*IN_DIM + A_DIM*F_DIM) {
    int j = id - F_DIM*IN_DIM;
    wa1b[j] = f2bf(Wa1[j]);
  } else if (id < F_DIM*IN_DIM + A_DIM*F_DIM + NBAGS*257) {
    bagAcc[id - (F_DIM*IN_DIM + A_DIM*F_DIM)] = 0.f;
  }
}

// ---------- fused main (R8 verbatim — best known, 337 us total) ----------
__global__ __launch_bounds__(256, 2)
void mil_main(const float* __restrict__ feat,
              const unsigned short* __restrict__ w1b,
              const float* __restrict__ b1,
              const unsigned short* __restrict__ wa1b,
              const float* __restrict__ ba1,
              const float* __restrict__ wa2,
              const float* __restrict__ ba2v,
              float* __restrict__ bagAcc)
{
  extern __shared__ char lds[];
  char* Abuf[2] = { lds, lds + 8192 };
  char* Bbuf[2] = { lds + 16384, lds + 32768 };
  char* HsB  = lds;
  float* sc4  = (float*)(lds + 65536);
  float* evec = (float*)(lds + 65536 + 2048);
  float* Pp   = (float*)(lds + 65536 + 2048 + 512);

  const int tid  = threadIdx.x;
  const int wid  = tid >> 6;
  const int lane = tid & 63;
  const int l15  = lane & 15;
  const int l4   = lane >> 4;
  const int wm   = wid >> 1;
  const int wn   = wid & 1;
  const int bRow = blockIdx.x * ROWSB;

  const int arow = tid >> 1;
  const int ahalf = tid & 1;
  const float* aG = feat + (size_t)(bRow + arow) * IN_DIM + ahalf * 16;
  const int awb = arow * 64 + ahalf * 32;
  const int aswz = SWZ4(arow);

  const char* srcB[4];
  #pragma unroll
  for (int i = 0; i < 4; ++i){
    int Blin = wid*4096 + i*1024 + lane*16;
    int col  = Blin >> 6;
    int kb   = Blin & 63;
    srcB[i] = (const char*)w1b + (size_t)col*2048 + (kb ^ SWZ4(col));
  }

#define STAGEB(bb, t) do { \
    _Pragma("unroll") \
    for (int i_ = 0; i_ < 4; ++i_) \
      gload_lds16(srcB[i_] + (size_t)(t)*64, (bb) + wid*4096 + i_*1024); \
  } while(0)
#define LOADT(R, t) do { \
    const float* p_ = aG + (t)*32; \
    R[0] = *(const float4*)p_;  R[1] = *(const float4*)(p_ + 4); \
    R[2] = *(const float4*)(p_ + 8);  R[3] = *(const float4*)(p_ + 12); \
  } while(0)
#define CVTST(R, ab) do { \
    const float* v_ = (const float*)(R); \
    i32x4 w0_ = { (int)cvtpk(v_[0],  v_[1]),  (int)cvtpk(v_[2],  v_[3]), \
                  (int)cvtpk(v_[4],  v_[5]),  (int)cvtpk(v_[6],  v_[7]) }; \
    i32x4 w1_ = { (int)cvtpk(v_[8],  v_[9]),  (int)cvtpk(v_[10], v_[11]), \
                  (int)cvtpk(v_[12], v_[13]), (int)cvtpk(v_[14], v_[15]) }; \
    *(i32x4*)((ab) + ((awb +  0) ^ aswz)) = w0_; \
    *(i32x4*)((ab) + ((awb + 16) ^ aswz)) = w1_; \
  } while(0)
#define COMPUTE(ab, bb) do { \
    short8 af_[4]; \
    _Pragma("unroll") \
    for (int mf_ = 0; mf_ < 4; ++mf_){ \
      int row_ = wm*64 + mf_*16 + l15; \
      af_[mf_] = *(const short8*)((ab) + (row_*64 + ((l4*16) ^ SWZ4(row_)))); \
    } \
    _Pragma("unroll") \
    for (int nf_ = 0; nf_ < 8; ++nf_){ \
      int col_ = wn*128 + nf_*16 + l15; \
      short8 bf_ = *(const short8*)((bb) + (col_*64 + ((l4*16) ^ SWZ4(col_)))); \
      _Pragma("unroll") \
      for (int mf_ = 0; mf_ < 4; ++mf_) \
        acc[mf_][nf_] = MFMA(af_[mf_], bf_, acc[mf_][nf_]); \
    } \
  } while(0)
#define KBAR(N) do { \
    asm volatile("s_waitcnt vmcnt(" #N ") lgkmcnt(0)" ::: "memory"); \
    __builtin_amdgcn_sched_barrier(0); \
    __builtin_amdgcn_s_barrier(); \
  } while(0)

  f32x4 acc[4][8];
  #pragma unroll
  for (int i = 0; i < 4; ++i)
    #pragma unroll
    for (int j = 0; j < 8; ++j) acc[i][j] = (f32x4){0.f, 0.f, 0.f, 0.f};

  float4 aR0[4], aR1[4];

  STAGEB(Bbuf[0], 0);
  LOADT(aR0, 0);
  LOADT(aR1, 1);
  CVTST(aR0, Abuf[0]);
  KBAR(2);

  for (int tp = 0; tp < 15; ++tp){
    const int t0 = tp*2, t1 = tp*2 + 1;
    STAGEB(Bbuf[1], t0 + 1);
    LOADT(aR0, t0 + 2);
    __builtin_amdgcn_sched_barrier(0);
    COMPUTE(Abuf[0], Bbuf[0]);
    CVTST(aR1, Abuf[1]);
    KBAR(4);
    STAGEB(Bbuf[0], t1 + 1);
    if (t1 + 2 < 32) LOADT(aR1, t1 + 2);
    __builtin_amdgcn_sched_barrier(0);
    COMPUTE(Abuf[1], Bbuf[1]);
    CVTST(aR0, Abuf[0]);
    KBAR(4);
  }
  STAGEB(Bbuf[1], 31);
  COMPUTE(Abuf[0], Bbuf[0]);
  CVTST(aR1, Abuf[1]);
  KBAR(0);
  COMPUTE(Abuf[1], Bbuf[1]);
  __syncthreads();
#undef STAGEB
#undef LOADT
#undef CVTST
#undef COMPUTE
#undef KBAR

  float b1v[8];
  #pragma unroll
  for (int nf = 0; nf < 8; ++nf) b1v[nf] = b1[wn*128 + nf*16 + l15];

  #pragma unroll
  for (int mf = 0; mf < 4; ++mf)
    #pragma unroll
    for (int nf = 0; nf < 8; ++nf)
      #pragma unroll
      for (int r = 0; r < 4; ++r){
        int row = wm*64 + mf*16 + l4*4 + r;
        int col = wn*128 + nf*16 + l15;
        float v = fmaxf(acc[mf][nf][r] + b1v[nf], 0.f);
        int by = (row*512 + col*2) ^ SWZH(row);
        *(unsigned short*)(HsB + by) = f2bf(v);
      }
  __syncthreads();

  f32x4 acc2[8][2];
  #pragma unroll
  for (int i = 0; i < 8; ++i)
    #pragma unroll
    for (int j = 0; j < 2; ++j) acc2[i][j] = (f32x4){0.f, 0.f, 0.f, 0.f};

  #pragma unroll
  for (int ks2 = 0; ks2 < 8; ++ks2){
    short8 hf[8], wf[2];
    #pragma unroll
    for (int mf = 0; mf < 8; ++mf){
      int row = mf*16 + l15;
      int by  = (row*512 + (ks2*32 + l4*8)*2) ^ SWZH(row);
      hf[mf] = *(const short8*)(HsB + by);
    }
    #pragma unroll
    for (int nf = 0; nf < 2; ++nf){
      int col = wid*32 + nf*16 + l15;
      wf[nf] = *(const short8*)(const void*)(wa1b + col*256 + ks2*32 + l4*8);
    }
    #pragma unroll
    for (int mf = 0; mf < 8; ++mf)
      #pragma unroll
      for (int nf = 0; nf < 2; ++nf)
        acc2[mf][nf] = MFMA(hf[mf], wf[nf], acc2[mf][nf]);
  }

  float ba1v[2], wa2v[2];
  #pragma unroll
  for (int nf = 0; nf < 2; ++nf){
    int col = wid*32 + nf*16 + l15;
    ba1v[nf] = ba1[col];
    wa2v[nf] = wa2[col];
  }
  #pragma unroll
  for (int mf = 0; mf < 8; ++mf)
    #pragma unroll
    for (int r = 0; r < 4; ++r){
      float p = tanh_fast(acc2[mf][0][r] + ba1v[0]) * wa2v[0]
              + tanh_fast(acc2[mf][1][r] + ba1v[1]) * wa2v[1];
      p += __shfl_xor(p, 1);
      p += __shfl_xor(p, 2);
      p += __shfl_xor(p, 4);
      p += __shfl_xor(p, 8);
      if (l15 == 0){
        int row = mf*16 + l4*4 + r;
        sc4[row*4 + wid] = p;
      }
    }
  __syncthreads();

  if (tid < 128){
    float s = sc4[tid*4+0] + sc4[tid*4+1] + sc4[tid*4+2] + sc4[tid*4+3] + ba2v[0];
    evec[tid] = __expf(s);
  }
  __syncthreads();

  {
    const int f0 = (tid & 127) << 1;
    const int g  = tid >> 7;
    float p0 = 0.f, p1 = 0.f;
    const int rbase = g << 6;
    #pragma unroll 8
    for (int i = 0; i < 64; ++i){
      const int r = rbase + i;
      const uint32_t hw = *(const uint32_t*)(HsB + ((r*512 + f0*2) ^ SWZH(r)));
      const float e = evec[r];
      p0 = fmaf(e, bf2f((unsigned short)(hw & 0xffffu)), p0);
      p1 = fmaf(e, bf2f((unsigned short)(hw >> 16)),     p1);
    }
    Pp[(g << 8) + f0]     = p0;
    Pp[(g << 8) + f0 + 1] = p1;
  }
  __syncthreads();

  const int bag = bRow >> 13;
  {
    float s = Pp[tid] + Pp[256 + tid];
    atomicAdd(&bagAcc[bag*257 + tid], s);
  }
  if (tid < 64){
    float se = evec[tid] + evec[tid + 64];
    se += __shfl_xor(se, 1);
    se += __shfl_xor(se, 2);
    se += __shfl_xor(se, 4);
    se += __shfl_xor(se, 8);
    se += __shfl_xor(se, 16);
    se += __shfl_xor(se, 32);
    if (tid == 0) atomicAdd(&bagAcc[bag*257 + 256], se);
  }
}

// ---------- head ----------
__global__ void head_kernel(const float* __restrict__ bagAcc,
                            const float* __restrict__ wh,
                            const float* __restrict__ bh,
                            float* __restrict__ out){
  int t = threadIdx.x;
  int b = t >> 1, d = t & 1;
  const float* P = bagAcc + b*257;
  float invE = 1.f / P[256];
  float acc = 0.f;
  for (int f = 0; f < 256; ++f) acc += P[f] * wh[d*256 + f];
  out[b*2 + d] = acc * invE + bh[d];
}

// ================= DIAGNOSTIC PROBES (write only to d_ws scratch) =================
// All: 512 blocks x 256 thr, LDS 70144 (R8 residency: 2 blocks/CU), slices
// bid*4 + (rep&3) cover all 2048 128-row tiles once per 4 reps.

// P1: A-stream, R8's reg-load pattern (lane-pair 4KB stride, 16B segments). 5 passes.
__global__ __launch_bounds__(256, 2)
void probe_a_reg(const float* __restrict__ feat, float* __restrict__ sink){
  extern __shared__ char lds[];
  const int tid = threadIdx.x;
  const int arow = tid >> 1, ahalf = tid & 1;
  f32x4 s = (f32x4){0.f,0.f,0.f,0.f};
  for (int rep = 0; rep < 20; ++rep){
    const int bRow = (blockIdx.x*4 + (rep & 3)) * 128;
    const float* aG = feat + (size_t)(bRow + arow) * IN_DIM + ahalf * 16;
    for (int t = 0; t < 32; ++t){
      const float* p = aG + t*32;
      s += *(const f32x4*)p;
      s += *(const f32x4*)(p + 4);
      s += *(const f32x4*)(p + 8);
      s += *(const f32x4*)(p + 12);
    }
  }
  sink[blockIdx.x*256 + tid] = s[0]+s[1]+s[2]+s[3];
  lds[0] = 0;  // keep lds alloc
}

// P2: A-stream via global_load_lds, linear dest (1KB/instr, 128B segments). 5 passes.
__global__ __launch_bounds__(256, 2)
void probe_a_dma(const float* __restrict__ feat, float* __restrict__ sink){
  extern __shared__ char lds[];
  const int tid = threadIdx.x;
  const int wid = tid >> 6;
  const int lane = tid & 63;
  for (int rep = 0; rep < 20; ++rep){
    const int bRow = (blockIdx.x*4 + (rep & 3)) * 128;
    const char* src[4];
    #pragma unroll
    for (int i = 0; i < 4; ++i){
      int Blin = wid*4096 + i*1024 + lane*16;
      int row  = Blin >> 7;           // 8 rows per 1KB instr, 128B each
      src[i] = (const char*)feat + (size_t)(bRow + row)*4096 + (Blin & 127);
    }
    for (int t = 0; t < 32; ++t){
      char* dst = lds + (t & 1)*16384 + wid*4096;
      #pragma unroll
      for (int i = 0; i < 4; ++i)
        gload_lds16(src[i] + (size_t)t*128, dst + i*1024);
      asm volatile("s_waitcnt vmcnt(8)" ::: "memory");   // ~2 steps in flight
    }
  }
  asm volatile("s_waitcnt vmcnt(0)" ::: "memory");
  __syncthreads();
  sink[blockIdx.x*256 + tid] = *(const float*)(lds + ((tid*64) & 8191));
}

// P3: R8 staging cadence exactly (A reg-load + cvt + ds_write, B gload, KBAR(4)),
// no MFMA. 4 passes.
__global__ __launch_bounds__(256, 2)
void probe_st(const float* __restrict__ feat, const unsigned short* __restrict__ w1b,
              float* __restrict__ sink){
  extern __shared__ char lds[];
  char* Abuf[2] = { lds, lds + 8192 };
  char* Bbuf[2] = { lds + 16384, lds + 32768 };
  const int tid = threadIdx.x;
  const int wid = tid >> 6;
  const int lane = tid & 63;
  const int arow = tid >> 1, ahalf = tid & 1;
  const int awb = arow*64 + ahalf*32;
  const int aswz = SWZ4(arow);
  const char* srcB[4];
  #pragma unroll
  for (int i = 0; i < 4; ++i){
    int Blin = wid*4096 + i*1024 + lane*16;
    int col  = Blin >> 6;
    srcB[i] = (const char*)w1b + (size_t)col*2048 + ((Blin & 63) ^ SWZ4(col));
  }
#define STAGEB(bb, t) do { _Pragma("unroll") for (int i_=0;i_<4;++i_) \
    gload_lds16(srcB[i_] + (size_t)(t)*64, (bb) + wid*4096 + i_*1024); } while(0)
#define LOADT(R, t) do { const float* p_ = aG + (t)*32; \
    R[0]=*(const float4*)p_; R[1]=*(const float4*)(p_+4); \
    R[2]=*(const float4*)(p_+8); R[3]=*(const float4*)(p_+12); } while(0)
#define CVTST(R, ab) do { const float* v_ = (const float*)(R); \
    i32x4 w0_ = { (int)cvtpk(v_[0],v_[1]),(int)cvtpk(v_[2],v_[3]), \
                  (int)cvtpk(v_[4],v_[5]),(int)cvtpk(v_[6],v_[7]) }; \
    i32x4 w1_ = { (int)cvtpk(v_[8],v_[9]),(int)cvtpk(v_[10],v_[11]), \
                  (int)cvtpk(v_[12],v_[13]),(int)cvtpk(v_[14],v_[15]) }; \
    *(i32x4*)((ab) + ((awb+0)^aswz)) = w0_; \
    *(i32x4*)((ab) + ((awb+16)^aswz)) = w1_; } while(0)
#define KBAR(N) do { asm volatile("s_waitcnt vmcnt(" #N ") lgkmcnt(0)" ::: "memory"); \
    __builtin_amdgcn_sched_barrier(0); __builtin_amdgcn_s_barrier(); } while(0)
  for (int rep = 0; rep < 16; ++rep){
    const int bRow = (blockIdx.x*4 + (rep & 3)) * 128;
    const float* aG = feat + (size_t)(bRow + arow) * IN_DIM + ahalf * 16;
    float4 aR0[4], aR1[4];
    STAGEB(Bbuf[0], 0);
    LOADT(aR0, 0);
    LOADT(aR1, 1);
    CVTST(aR0, Abuf[0]);
    KBAR(2);
    for (int tp = 0; tp < 15; ++tp){
      const int t0 = tp*2, t1 = tp*2 + 1;
      STAGEB(Bbuf[1], t0 + 1);
      LOADT(aR0, t0 + 2);
      __builtin_amdgcn_sched_barrier(0);
      CVTST(aR1, Abuf[1]);
      KBAR(4);
      STAGEB(Bbuf[0], t1 + 1);
      if (t1 + 2 < 32) LOADT(aR1, t1 + 2);
      __builtin_amdgcn_sched_barrier(0);
      CVTST(aR0, Abuf[0]);
      KBAR(4);
    }
    STAGEB(Bbuf[1], 31);
    CVTST(aR1, Abuf[1]);
    KBAR(0);
    __syncthreads();
  }
  sink[blockIdx.x*256 + tid] = *(const float*)(lds + ((tid*64) & 32767));
#undef STAGEB
#undef LOADT
#undef CVTST
#undef KBAR
}

// P4: R8 K-loop exactly (staging + MFMA), no epilogue. 3 passes.
__global__ __launch_bounds__(256, 2)
void probe_kl(const float* __restrict__ feat, const unsigned short* __restrict__ w1b,
              float* __restrict__ sink){
  extern __shared__ char lds[];
  char* Abuf[2] = { lds, lds + 8192 };
  char* Bbuf[2] = { lds + 16384, lds + 32768 };
  const int tid = threadIdx.x;
  const int wid = tid >> 6;
  const int lane = tid & 63;
  const int l15 = lane & 15;
  const int l4  = lane >> 4;
  const int wm = wid >> 1, wn = wid & 1;
  const int arow = tid >> 1, ahalf = tid & 1;
  const int awb = arow*64 + ahalf*32;
  const int aswz = SWZ4(arow);
  const char* srcB[4];
  #pragma unroll
  for (int i = 0; i < 4; ++i){
    int Blin = wid*4096 + i*1024 + lane*16;
    int col  = Blin >> 6;
    srcB[i] = (const char*)w1b + (size_t)col*2048 + ((Blin & 63) ^ SWZ4(col));
  }
#define STAGEB(bb, t) do { _Pragma("unroll") for (int i_=0;i_<4;++i_) \
    gload_lds16(srcB[i_] + (size_t)(t)*64, (bb) + wid*4096 + i_*1024); } while(0)
#define LOADT(R, t) do { const float* p_ = aG + (t)*32; \
    R[0]=*(const float4*)p_; R[1]=*(const float4*)(p_+4); \
    R[2]=*(const float4*)(p_+8); R[3]=*(const float4*)(p_+12); } while(0)
#define CVTST(R, ab) do { const float* v_ = (const float*)(R); \
    i32x4 w0_ = { (int)cvtpk(v_[0],v_[1]),(int)cvtpk(v_[2],v_[3]), \
                  (int)cvtpk(v_[4],v_[5]),(int)cvtpk(v_[6],v_[7]) }; \
    i32x4 w1_ = { (int)cvtpk(v_[8],v_[9]),(int)cvtpk(v_[10],v_[11]), \
                  (int)cvtpk(v_[12],v_[13]),(int)cvtpk(v_[14],v_[15]) }; \
    *(i32x4*)((ab) + ((awb+0)^aswz)) = w0_; \
    *(i32x4*)((ab) + ((awb+16)^aswz)) = w1_; } while(0)
#define COMPUTE(ab, bb) do { short8 af_[4]; \
    _Pragma("unroll") for (int mf_=0; mf_<4; ++mf_){ \
      int row_ = wm*64 + mf_*16 + l15; \
      af_[mf_] = *(const short8*)((ab) + (row_*64 + ((l4*16) ^ SWZ4(row_)))); } \
    _Pragma("unroll") for (int nf_=0; nf_<8; ++nf_){ \
      int col_ = wn*128 + nf_*16 + l15; \
      short8 bf_ = *(const short8*)((bb) + (col_*64 + ((l4*16) ^ SWZ4(col_)))); \
      _Pragma("unroll") for (int mf_=0; mf_<4; ++mf_) \
        acc[mf_][nf_] = MFMA(af_[mf_], bf_, acc[mf_][nf_]); } } while(0)
#define KBAR(N) do { asm volatile("s_waitcnt vmcnt(" #N ") lgkmcnt(0)" ::: "memory"); \
    __builtin_amdgcn_sched_barrier(0); __builtin_amdgcn_s_barrier(); } while(0)
  f32x4 acc[4][8];
  #pragma unroll
  for (int i = 0; i < 4; ++i)
    #pragma unroll
    for (int j = 0; j < 8; ++j) acc[i][j] = (f32x4){0.f,0.f,0.f,0.f};
  for (int rep = 0; rep < 12; ++rep){
    const int bRow = (blockIdx.x*4 + (rep & 3)) * 128;
    const float* aG = feat + (size_t)(bRow + arow) * IN_DIM + ahalf * 16;
    float4 aR0[4], aR1[4];
    STAGEB(Bbuf[0], 0);
    LOADT(aR0, 0);
    LOADT(aR1, 1);
    CVTST(aR0, Abuf[0]);
    KBAR(2);
    for (int tp = 0; tp < 15; ++tp){
      const int t0 = tp*2, t1 = tp*2 + 1;
      STAGEB(Bbuf[1], t0 + 1);
      LOADT(aR0, t0 + 2);
      __builtin_amdgcn_sched_barrier(0);
      COMPUTE(Abuf[0], Bbuf[0]);
      CVTST(aR1, Abuf[1]);
      KBAR(4);
      STAGEB(Bbuf[0], t1 + 1);
      if (t1 + 2 < 32) LOADT(aR1, t1 + 2);
      __builtin_amdgcn_sched_barrier(0);
      COMPUTE(Abuf[1], Bbuf[1]);
      CVTST(aR0, Abuf[0]);
      KBAR(4);
    }
    STAGEB(Bbuf[1], 31);
    COMPUTE(Abuf[0], Bbuf[0]);
    CVTST(aR1, Abuf[1]);
    KBAR(0);
    COMPUTE(Abuf[1], Bbuf[1]);
    __syncthreads();
  }
  float s = 0.f;
  #pragma unroll
  for (int i = 0; i < 4; ++i)
    #pragma unroll
    for (int j = 0; j < 8; ++j)
      s += acc[i][j][0] + acc[i][j][1] + acc[i][j][2] + acc[i][j][3];
  sink[blockIdx.x*256 + tid] = s;
#undef STAGEB
#undef LOADT
#undef CVTST
#undef COMPUTE
#undef KBAR
}

extern "C" void kernel_launch(void* const* d_in, const int* in_sizes, int n_in,
                              void* d_out, int out_size, void* d_ws, size_t ws_size,
                              hipStream_t stream){
  const float* feat = (const float*)d_in[0];
  const float* W1   = (const float*)d_in[1];
  const float* b1   = (const float*)d_in[2];
  const float* Wa1  = (const float*)d_in[3];
  const float* ba1  = (const float*)d_in[4];
  const float* Wa2  = (const float*)d_in[5];
  const float* ba2  = (const float*)d_in[6];
  const float* Wh   = (const float*)d_in[7];
  const float* bh   = (const float*)d_in[8];

  unsigned short* w1b  = (unsigned short*)d_ws;                        // 512 KB
  unsigned short* wa1b = (unsigned short*)((char*)d_ws + 524288);      // 64 KB
  float* bagAcc        = (float*)((char*)d_ws + 589824);               // 32*257 f32
  float* sink1         = (float*)((char*)d_ws + 2097152);
  float* sink2         = (float*)((char*)d_ws + 2621440);
  float* sink3         = (float*)((char*)d_ws + 3145728);
  float* sink4         = (float*)((char*)d_ws + 3670016);

  prep_kernel<<<1185, 256, 0, stream>>>(W1, Wa1, w1b, wa1b, bagAcc);

  mil_main<<<NBLK, 256, 70144, stream>>>(feat, w1b, b1, wa1b, ba1,
                                         Wa2, ba2, bagAcc);

  head_kernel<<<1, 64, 0, stream>>>(bagAcc, Wh, bh, (float*)d_out);

  // ---- diagnostic probes (timing read from rocprof; outputs discarded) ----
  probe_a_reg<<<512, 256, 70144, stream>>>(feat, sink1);
  probe_a_dma<<<512, 256, 70144, stream>>>(feat, sink2);
  probe_st  <<<512, 256, 70144, stream>>>(feat, w1b, sink3);
  probe_kl  <<<512, 256, 70144, stream>>>(feat, w1b, sink4);
}

// Round 13
// 433.557 us; speedup vs baseline: 9.0741x; 9.0741x over previous
//
#include <hip/hip_runtime.h>
#include <cstdint>
#include <cstddef>

typedef short short8 __attribute__((ext_vector_type(8)));
typedef float f32x4 __attribute__((ext_vector_type(4)));
typedef int   i32x4 __attribute__((ext_vector_type(4)));

#define NPATCH 262144
#define NBAGS  32
#define IN_DIM 1024
#define F_DIM  256
#define A_DIM  128
#define ROWSB  64
#define NBLK   (NPATCH / ROWSB)    // 4096

__device__ __forceinline__ unsigned short f2bf(float f){
  uint32_t u = __builtin_bit_cast(uint32_t, f);
  u += 0x7fffu + ((u >> 16) & 1u);
  return (unsigned short)(u >> 16);
}
__device__ __forceinline__ float bf2f(unsigned short h){
  return __builtin_bit_cast(float, (uint32_t)h << 16);
}
__device__ __forceinline__ float tanh_fast(float x){
  float e = __expf(2.f * x);
  return (e - 1.f) * __builtin_amdgcn_rcpf(e + 1.f);
}
__device__ __forceinline__ uint32_t cvtpk(float a, float b){
  uint32_t r;
  asm("v_cvt_pk_bf16_f32 %0, %1, %2" : "=v"(r) : "v"(a), "v"(b));
  return r;
}
__device__ __forceinline__ void gload_lds16(const void* g, void* l){
  __builtin_amdgcn_global_load_lds((const __attribute__((address_space(1))) void*)g,
                                   (__attribute__((address_space(3))) void*)l, 16, 0, 0);
}

#define MFMA(a,b,c) __builtin_amdgcn_mfma_f32_16x16x32_bf16((a),(b),(c),0,0,0)
#define SWZH(r) (((r) & 7) << 4)   // 512B bf16 Hs rows

// ---------- prep: W1, Wa1 -> bf16 in ws; zero bag accumulators ----------
__global__ void prep_kernel(const float* __restrict__ W1, const float* __restrict__ Wa1,
                            unsigned short* __restrict__ w1b, unsigned short* __restrict__ wa1b,
                            float* __restrict__ bagAcc){
  int id = blockIdx.x * 256 + threadIdx.x;
  if (id < F_DIM*IN_DIM) {
    w1b[id] = f2bf(W1[id]);
  } else if (id < F_DIM*IN_DIM + A_DIM*F_DIM) {
    int j = id - F_DIM*IN_DIM;
    wa1b[j] = f2bf(Wa1[j]);
  } else if (id < F_DIM*IN_DIM + A_DIM*F_DIM + NBAGS*257) {
    bagAcc[id - (F_DIM*IN_DIM + A_DIM*F_DIM)] = 0.f;
  }
}

// ---------- fused main ----------
// 64 rows/block, 256 threads, 4 waves; wave = 16 rows x ALL 256 cols
// (acc[16] f32x4 = 64 VGPR).
// GEMM1: A NEVER touches LDS — per step (BK=32) each thread loads its MFMA
// A-fragment directly from HBM (32B: row = bRow+wid*16+l15, k = t*32+l4*8),
// cvtpk -> bf16 — probe_a_reg's pattern, which measured AT the HBM floor.
// B: one 64KB LDS tile [256 cols][128 k] bf16 per 4-step group (8 stages),
// swizzled source, 2-way-free bank pattern. Barriers ONLY at group
// boundaries — in-group the only VMEM is the A stream (depth-1 ping-pong,
// compiler vmcnt(2) covers one-step-old loads). 16 ds_read_b128 + 16 MFMA
// + 1 A-load + 4 cvtpk per step.
// LDS 68864 B: Btile 64K @0 | sc4[64][4] @64K | evec[64] | Pp[2][256]
//   epilogue overlay: Hs[64][256] bf16 @0 (32K). 2 blocks/CU.
__global__ __launch_bounds__(256, 2)
void mil_main(const float* __restrict__ feat,
              const unsigned short* __restrict__ w1b,
              const float* __restrict__ b1,
              const unsigned short* __restrict__ wa1b,
              const float* __restrict__ ba1,
              const float* __restrict__ wa2,
              const float* __restrict__ ba2v,
              float* __restrict__ bagAcc)
{
  extern __shared__ char lds[];
  char* Bt   = lds;                        // [256][128k] bf16, swizzled
  char* HsB  = lds;                        // epilogue overlay
  float* sc4  = (float*)(lds + 65536);     // [64][4]
  float* evec = (float*)(lds + 65536 + 1024);
  float* Pp   = (float*)(lds + 65536 + 1024 + 256);

  const int tid  = threadIdx.x;
  const int wid  = tid >> 6;
  const int lane = tid & 63;
  const int l15  = lane & 15;
  const int l4   = lane >> 4;
  const int bRow = blockIdx.x * ROWSB;

  // ---- A: direct HBM fragment loads (row = bRow + wid*16 + l15, k = t*32+l4*8)
  const float* aG = feat + (size_t)(bRow + wid*16 + l15) * IN_DIM + l4*8;

  // ---- B stage source bases (linear LDS dest, pre-swizzled source; rule 21)
  // dest D(i) = wid*16384 + i*1024 + lane*16 ; col = D>>8 ; kb = D&255
  // src byte  = col*2048 + g*256 + (kb ^ ((col&7)<<4))
  // i and i+2 differ by col+=8 (same swizzle) -> src += 16384.
  const char* w1c = (const char*)w1b;
  const char* srcB0, *srcB1;
  {
    int D0 = wid*16384 + lane*16;
    int c0 = D0 >> 8, k0 = D0 & 255;
    srcB0 = w1c + (size_t)c0*2048 + (k0 ^ ((c0 & 7) << 4));
    int D1 = D0 + 1024;
    int c1 = D1 >> 8, k1 = D1 & 255;
    srcB1 = w1c + (size_t)c1*2048 + (k1 ^ ((c1 & 7) << 4));
  }

#define STAGEB(g) do { \
    _Pragma("unroll") \
    for (int i_ = 0; i_ < 16; ++i_){ \
      const char* s_ = ((i_ & 1) ? srcB1 : srcB0) + (size_t)(i_ >> 1)*16384 + (g)*256; \
      gload_lds16(s_, Bt + wid*16384 + i_*1024); \
    } \
  } while(0)

#define LOADA(R, t) do { \
    const float* p_ = aG + (t)*32; \
    R[0] = *(const float4*)p_;  R[1] = *(const float4*)(p_ + 4); \
  } while(0)

#define AFRAG(af, R) do { \
    const float* v_ = (const float*)(R); \
    i32x4 w_ = { (int)cvtpk(v_[0], v_[1]), (int)cvtpk(v_[2], v_[3]), \
                 (int)cvtpk(v_[4], v_[5]), (int)cvtpk(v_[6], v_[7]) }; \
    af = __builtin_bit_cast(short8, w_); \
  } while(0)

  f32x4 acc[16];
  #pragma unroll
  for (int j = 0; j < 16; ++j) acc[j] = (f32x4){0.f, 0.f, 0.f, 0.f};

  float4 aR0[2], aR1[2];
  LOADA(aR0, 0);

  const int swzk = (l15 & 7) << 4;          // bank swizzle (bits 4-6)
  const int rbase = l15 * 256;              // col = nf*16 + l15 -> nf*4096 + rbase

  for (int g = 0; g < 8; ++g){
    if (g){
      // waves finished reading group g-1 (own ds_reads drained), then barrier
      asm volatile("s_waitcnt lgkmcnt(0)" ::: "memory");
      __builtin_amdgcn_sched_barrier(0);
      __builtin_amdgcn_s_barrier();
    }
    STAGEB(g);
    __syncthreads();    // vmcnt(0)+lgkmcnt(0)+barrier: B tile ready

    // 4 barrier-free steps (BK=32 each); only VMEM in-group = A stream
    #pragma unroll
    for (int s = 0; s < 4; ++s){
      const int t = g*4 + s;
      if (t + 1 < 32){
        if (s & 1) LOADA(aR0, t + 1); else LOADA(aR1, t + 1);
      }
      short8 af;
      if (s & 1) AFRAG(af, aR1); else AFRAG(af, aR0);
      const int off = ((s*64 + l4*16) ^ swzk) + rbase;
      #pragma unroll
      for (int nf = 0; nf < 16; ++nf){
        short8 bf = *(const short8*)(Bt + nf*4096 + off);
        acc[nf] = MFMA(af, bf, acc[nf]);
      }
    }
  }
  __syncthreads();   // K-loop done; Bt region free for Hs overlay

#undef STAGEB
#undef LOADA
#undef AFRAG

  // -------- epilogue 1: bias + relu, h -> Hs[64][256] bf16 (swizzled) --------
  #pragma unroll
  for (int nf = 0; nf < 16; ++nf){
    float b1v = b1[nf*16 + l15];
    #pragma unroll
    for (int r = 0; r < 4; ++r){
      int row = wid*16 + l4*4 + r;
      int col = nf*16 + l15;
      float v = fmaxf(acc[nf][r] + b1v, 0.f);
      int by = (row*512 + col*2) ^ SWZH(row);
      *(unsigned short*)(HsB + by) = f2bf(v);
    }
  }
  __syncthreads();

  // -------- GEMM2: a = h @ Wa1.T (M=64, N=128, K=256); Wa1 frags from L2 --------
  f32x4 acc2[4][2];
  #pragma unroll
  for (int i = 0; i < 4; ++i)
    #pragma unroll
    for (int j = 0; j < 2; ++j) acc2[i][j] = (f32x4){0.f, 0.f, 0.f, 0.f};

  #pragma unroll
  for (int ks2 = 0; ks2 < 8; ++ks2){
    short8 hf[4], wf[2];
    #pragma unroll
    for (int mf = 0; mf < 4; ++mf){
      int row = mf*16 + l15;
      int by  = (row*512 + (ks2*32 + l4*8)*2) ^ SWZH(row);
      hf[mf] = *(const short8*)(HsB + by);
    }
    #pragma unroll
    for (int nf = 0; nf < 2; ++nf){
      int col = wid*32 + nf*16 + l15;
      wf[nf] = *(const short8*)(const void*)(wa1b + col*256 + ks2*32 + l4*8);
    }
    #pragma unroll
    for (int mf = 0; mf < 4; ++mf)
      #pragma unroll
      for (int nf = 0; nf < 2; ++nf)
        acc2[mf][nf] = MFMA(hf[mf], wf[nf], acc2[mf][nf]);
  }

  // -------- scores: tanh, dot Wa2, reduce across 16-lane col groups --------
  float ba1v[2], wa2v[2];
  #pragma unroll
  for (int nf = 0; nf < 2; ++nf){
    int col = wid*32 + nf*16 + l15;
    ba1v[nf] = ba1[col];
    wa2v[nf] = wa2[col];
  }
  #pragma unroll
  for (int mf = 0; mf < 4; ++mf)
    #pragma unroll
    for (int r = 0; r < 4; ++r){
      float p = tanh_fast(acc2[mf][0][r] + ba1v[0]) * wa2v[0]
              + tanh_fast(acc2[mf][1][r] + ba1v[1]) * wa2v[1];
      p += __shfl_xor(p, 1);
      p += __shfl_xor(p, 2);
      p += __shfl_xor(p, 4);
      p += __shfl_xor(p, 8);
      if (l15 == 0){
        int row = mf*16 + l4*4 + r;
        sc4[row*4 + wid] = p;
      }
    }
  __syncthreads();

  if (tid < 64){
    float s = sc4[tid*4+0] + sc4[tid*4+1] + sc4[tid*4+2] + sc4[tid*4+3] + ba2v[0];
    evec[tid] = __expf(s);   // |s| <= ~2.2 (tanh-bounded) — no max-subtraction needed
  }
  __syncthreads();

  // -------- weighted partial reduce: P[f] = sum_r e[r]*h[r][f] --------
  {
    const int f0 = (tid & 127) << 1;
    const int g  = tid >> 7;           // 2 row groups of 32
    float p0 = 0.f, p1 = 0.f;
    const int rbase2 = g << 5;
    #pragma unroll 8
    for (int i = 0; i < 32; ++i){
      const int r = rbase2 + i;
      const uint32_t hw = *(const uint32_t*)(HsB + ((r*512 + f0*2) ^ SWZH(r)));
      const float e = evec[r];
      p0 = fmaf(e, bf2f((unsigned short)(hw & 0xffffu)), p0);
      p1 = fmaf(e, bf2f((unsigned short)(hw >> 16)),     p1);
    }
    Pp[(g << 8) + f0]     = p0;
    Pp[(g << 8) + f0 + 1] = p1;
  }
  __syncthreads();

  const int bag = bRow >> 13;   // 8192 rows per bag
  {
    float s = Pp[tid] + Pp[256 + tid];
    atomicAdd(&bagAcc[bag*257 + tid], s);
  }
  if (tid < 64){
    float se = evec[tid];
    se += __shfl_xor(se, 1);
    se += __shfl_xor(se, 2);
    se += __shfl_xor(se, 4);
    se += __shfl_xor(se, 8);
    se += __shfl_xor(se, 16);
    se += __shfl_xor(se, 32);
    if (tid == 0) atomicAdd(&bagAcc[bag*257 + 256], se);
  }
}

// ---------- head: out[b,d] = (P[b]/E[b]) . Wh[d] + bh[d] ----------
__global__ void head_kernel(const float* __restrict__ bagAcc,
                            const float* __restrict__ wh,
                            const float* __restrict__ bh,
                            float* __restrict__ out){
  int t = threadIdx.x;          // 64 threads: b = t>>1, d = t&1
  int b = t >> 1, d = t & 1;
  const float* P = bagAcc + b*257;
  float invE = 1.f / P[256];
  float acc = 0.f;
  for (int f = 0; f < 256; ++f) acc += P[f] * wh[d*256 + f];
  out[b*2 + d] = acc * invE + bh[d];
}

extern "C" void kernel_launch(void* const* d_in, const int* in_sizes, int n_in,
                              void* d_out, int out_size, void* d_ws, size_t ws_size,
                              hipStream_t stream){
  const float* feat = (const float*)d_in[0];
  const float* W1   = (const float*)d_in[1];
  const float* b1   = (const float*)d_in[2];
  const float* Wa1  = (const float*)d_in[3];
  const float* ba1  = (const float*)d_in[4];
  const float* Wa2  = (const float*)d_in[5];
  const float* ba2  = (const float*)d_in[6];
  const float* Wh   = (const float*)d_in[7];
  const float* bh   = (const float*)d_in[8];
  // d_in[9]: bag_sizes — uniform 8192 (N_PATCHES/N_BAGS), bags contiguous.

  unsigned short* w1b  = (unsigned short*)d_ws;                        // 512 KB
  unsigned short* wa1b = (unsigned short*)((char*)d_ws + 524288);      // 64 KB
  float* bagAcc        = (float*)((char*)d_ws + 589824);               // 32*257 f32

  prep_kernel<<<1185, 256, 0, stream>>>(W1, Wa1, w1b, wa1b, bagAcc);

  const size_t ldsBytes = 65536 + 1024 + 256 + 2048;   // 68864
  mil_main<<<NBLK, 256, ldsBytes, stream>>>(feat, w1b, b1, wa1b, ba1,
                                            Wa2, ba2, bagAcc);

  head_kernel<<<1, 64, 0, stream>>>(bagAcc, Wh, bh, (float*)d_out);
}

// Round 14
// 289.828 us; speedup vs baseline: 13.5741x; 1.4959x over previous
//
#include <hip/hip_runtime.h>
#include <cstdint>
#include <cstddef>

typedef short short8 __attribute__((ext_vector_type(8)));
typedef float f32x4 __attribute__((ext_vector_type(4)));
typedef int   i32x4 __attribute__((ext_vector_type(4)));

#define NPATCH 262144
#define NBAGS  32
#define IN_DIM 1024
#define F_DIM  256
#define A_DIM  128
#define ROWSB  128
#define NBLK   (NPATCH / ROWSB)    // 2048

__device__ __forceinline__ unsigned short f2bf(float f){
  uint32_t u = __builtin_bit_cast(uint32_t, f);
  u += 0x7fffu + ((u >> 16) & 1u);
  return (unsigned short)(u >> 16);
}
__device__ __forceinline__ float bf2f(unsigned short h){
  return __builtin_bit_cast(float, (uint32_t)h << 16);
}
__device__ __forceinline__ float tanh_fast(float x){
  float e = __expf(2.f * x);
  return (e - 1.f) * __builtin_amdgcn_rcpf(e + 1.f);
}
__device__ __forceinline__ uint32_t cvtpk(float a, float b){
  uint32_t r;
  asm("v_cvt_pk_bf16_f32 %0, %1, %2" : "=v"(r) : "v"(a), "v"(b));
  return r;
}
__device__ __forceinline__ void gload_lds16(const void* g, void* l){
  __builtin_amdgcn_global_load_lds((const __attribute__((address_space(1))) void*)g,
                                   (__attribute__((address_space(3))) void*)l, 16, 0, 0);
}

#define MFMA(a,b,c) __builtin_amdgcn_mfma_f32_16x16x32_bf16((a),(b),(c),0,0,0)
#define SWZH(r) (((r) & 7) << 4)   // 512B bf16 Hs rows

// ---------- prep: W1, Wa1 -> bf16 in ws; zero bag accumulators ----------
__global__ void prep_kernel(const float* __restrict__ W1, const float* __restrict__ Wa1,
                            unsigned short* __restrict__ w1b, unsigned short* __restrict__ wa1b,
                            float* __restrict__ bagAcc){
  int id = blockIdx.x * 256 + threadIdx.x;
  if (id < F_DIM*IN_DIM) {
    w1b[id] = f2bf(W1[id]);
  } else if (id < F_DIM*IN_DIM + A_DIM*F_DIM) {
    int j = id - F_DIM*IN_DIM;
    wa1b[j] = f2bf(Wa1[j]);
  } else if (id < F_DIM*IN_DIM + A_DIM*F_DIM + NBAGS*257) {
    bagAcc[id - (F_DIM*IN_DIM + A_DIM*F_DIM)] = 0.f;
  }
}

// ---------- fused main ----------
// 128 rows/block, 256 threads, 4 waves; wave = 32 rows x ALL 256 cols
// (acc[2][16] f32x4 = 128 VGPR). A rows are wave-private -> A read ONCE.
// GEMM1: 16 groups of BK=64 (2 MFMA-steps of k=32 each).
//   A: pure register stream (probe-validated at HBM floor): per step each
//      thread holds 2 rows x 32B fp32, depth-2 ping-pong, consume-then-reload.
//   B: [256 cols][64k] bf16 tile (32KB), DOUBLE-buffered: stage(g+1) issued
//      at group start via 8 gload_lds (linear dest, pre-swizzled src),
//      retired by counted vmcnt(8) at group END -> full group of overlap.
//   One barrier + one counted wait per group (16 total). No A ds_writes.
// B-read swizzle: phys k-byte = klog ^ ((col&7)<<4) -> uniform 8 words/bank.
// LDS 70144: Bt0 @0 (32K) | Bt1 @32K | epilogue overlay: Hs[128][256] @0
//   (64K) | sc4[128][4] @64K | evec[128] @+2048 | Pp[2][256] @+2560.
__global__ __launch_bounds__(256, 2)
void mil_main(const float* __restrict__ feat,
              const unsigned short* __restrict__ w1b,
              const float* __restrict__ b1,
              const unsigned short* __restrict__ wa1b,
              const float* __restrict__ ba1,
              const float* __restrict__ wa2,
              const float* __restrict__ ba2v,
              float* __restrict__ bagAcc)
{
  extern __shared__ char lds[];
  char* Bt0 = lds;                      // [256][128B] bf16, swizzled k
  char* Bt1 = lds + 32768;
  char* HsB = lds;                      // epilogue overlay
  float* sc4  = (float*)(lds + 65536);
  float* evec = (float*)(lds + 65536 + 2048);
  float* Pp   = (float*)(lds + 65536 + 2048 + 512);

  const int tid  = threadIdx.x;
  const int wid  = tid >> 6;
  const int lane = tid & 63;
  const int l15  = lane & 15;
  const int l4   = lane >> 4;
  const int bRow = blockIdx.x * ROWSB;
  const int wRow = wid * 32;            // this wave's private 32 rows

  // ---- A register stream: rows wRow+l15 and wRow+16+l15, k-chunk l4*8 ----
  const float* aG0 = feat + (size_t)(bRow + wRow + l15) * IN_DIM + l4*8;
  const float* aG1 = aG0 + (size_t)16 * IN_DIM;

  // ---- B stage source (linear LDS dest, pre-swizzled global src; rule 21) --
  // dest D(i) = wid*8192 + i*1024 + lane*16: col = D>>7 = wid*64+i*8+(lane>>3),
  // kb_phys = (lane&7)*16. src = w1b + col*2048 + g*128 + (kb ^ ((col&7)<<4)).
  const char* srcB = (const char*)w1b
      + (size_t)(wid*64 + (lane >> 3)) * 2048
      + (((lane & 7) * 16) ^ (((lane >> 3) & 7) << 4));

#define STAGEB(bb, g) do { \
    _Pragma("unroll") \
    for (int i_ = 0; i_ < 8; ++i_) \
      gload_lds16(srcB + (size_t)i_*16384 + (size_t)(g)*128, \
                  (bb) + wid*8192 + i_*1024); \
  } while(0)

#define LOADA(R, t) do { \
    const float* p0_ = aG0 + (t)*32; \
    const float* p1_ = aG1 + (t)*32; \
    R[0] = *(const float4*)p0_;  R[1] = *(const float4*)(p0_ + 4); \
    R[2] = *(const float4*)p1_;  R[3] = *(const float4*)(p1_ + 4); \
  } while(0)

#define AFRAG2(a0, a1, R) do { \
    const float* v_ = (const float*)(R); \
    i32x4 w0_ = { (int)cvtpk(v_[0],  v_[1]),  (int)cvtpk(v_[2],  v_[3]), \
                  (int)cvtpk(v_[4],  v_[5]),  (int)cvtpk(v_[6],  v_[7]) }; \
    i32x4 w1_ = { (int)cvtpk(v_[8],  v_[9]),  (int)cvtpk(v_[10], v_[11]), \
                  (int)cvtpk(v_[12], v_[13]), (int)cvtpk(v_[14], v_[15]) }; \
    a0 = __builtin_bit_cast(short8, w0_); \
    a1 = __builtin_bit_cast(short8, w1_); \
  } while(0)

  f32x4 acc[2][16];
  #pragma unroll
  for (int i = 0; i < 2; ++i)
    #pragma unroll
    for (int j = 0; j < 16; ++j) acc[i][j] = (f32x4){0.f, 0.f, 0.f, 0.f};

  float4 aR0[4], aR1[4];   // A(t even) / A(t odd), 2 rows x 32B each

  // prologue: stage B(0) (oldest), A(0), A(1); retire stage only; barrier
  STAGEB(Bt0, 0);
  LOADA(aR0, 0);
  LOADA(aR1, 1);
  asm volatile("s_waitcnt vmcnt(8)" ::: "memory");
  __builtin_amdgcn_sched_barrier(0);
  __builtin_amdgcn_s_barrier();

  const int swzk = (l15 & 7) << 4;
  const int rb   = l15 * 128;

  for (int g = 0; g < 16; ++g){
    const char* bb = (g & 1) ? Bt1 : Bt0;
    char*       bn = (g & 1) ? Bt0 : Bt1;
    if (g < 15) STAGEB(bn, g + 1);      // in flight across the whole group
    __builtin_amdgcn_sched_barrier(0);

    #pragma unroll
    for (int s = 0; s < 2; ++s){        // t = 2g+s; t&1 == s
      short8 af0, af1;
      if (s == 0){
        AFRAG2(af0, af1, aR0);          // waits A(2g) (issued 2 steps ago)
        if (g < 15) LOADA(aR0, 2*g + 2);
      } else {
        AFRAG2(af0, af1, aR1);          // waits A(2g+1): older than stage(g+1)
        if (g < 15) LOADA(aR1, 2*g + 3);
      }
      __builtin_amdgcn_sched_barrier(0);
      const int off = rb + ((s*64 + l4*16) ^ swzk);
      #pragma unroll
      for (int nf = 0; nf < 16; ++nf){
        short8 bf = *(const short8*)(bb + nf*2048 + off);
        acc[0][nf] = MFMA(af0, bf, acc[0][nf]);
        acc[1][nf] = MFMA(af1, bf, acc[1][nf]);
      }
    }
    // retire stage(g+1) (oldest 8); keep the 8 A prefetch loads in flight
    asm volatile("s_waitcnt vmcnt(8)" ::: "memory");
    __builtin_amdgcn_sched_barrier(0);
    __builtin_amdgcn_s_barrier();
  }
  __syncthreads();   // full drain; Bt region free for Hs overlay

#undef STAGEB
#undef LOADA
#undef AFRAG2

  // -------- epilogue 1: bias + relu, h -> Hs[128][256] bf16 (swizzled) --------
  #pragma unroll
  for (int nf = 0; nf < 16; ++nf){
    float b1v = b1[nf*16 + l15];
    #pragma unroll
    for (int mf = 0; mf < 2; ++mf)
      #pragma unroll
      for (int r = 0; r < 4; ++r){
        int row = wRow + mf*16 + l4*4 + r;
        int col = nf*16 + l15;
        float v = fmaxf(acc[mf][nf][r] + b1v, 0.f);
        int by = (row*512 + col*2) ^ SWZH(row);
        *(unsigned short*)(HsB + by) = f2bf(v);
      }
  }
  __syncthreads();

  // -------- GEMM2: a = h @ Wa1.T (M=128, N=128, K=256); Wa1 from L2 --------
  f32x4 acc2[8][2];
  #pragma unroll
  for (int i = 0; i < 8; ++i)
    #pragma unroll
    for (int j = 0; j < 2; ++j) acc2[i][j] = (f32x4){0.f, 0.f, 0.f, 0.f};

  #pragma unroll
  for (int ks2 = 0; ks2 < 8; ++ks2){
    short8 hf[8], wf[2];
    #pragma unroll
    for (int mf = 0; mf < 8; ++mf){
      int row = mf*16 + l15;
      int by  = (row*512 + (ks2*32 + l4*8)*2) ^ SWZH(row);
      hf[mf] = *(const short8*)(HsB + by);
    }
    #pragma unroll
    for (int nf = 0; nf < 2; ++nf){
      int col = wid*32 + nf*16 + l15;
      wf[nf] = *(const short8*)(const void*)(wa1b + col*256 + ks2*32 + l4*8);
    }
    #pragma unroll
    for (int mf = 0; mf < 8; ++mf)
      #pragma unroll
      for (int nf = 0; nf < 2; ++nf)
        acc2[mf][nf] = MFMA(hf[mf], wf[nf], acc2[mf][nf]);
  }

  // -------- scores: tanh, dot Wa2, reduce across 16-lane col groups --------
  float ba1v[2], wa2v[2];
  #pragma unroll
  for (int nf = 0; nf < 2; ++nf){
    int col = wid*32 + nf*16 + l15;
    ba1v[nf] = ba1[col];
    wa2v[nf] = wa2[col];
  }
  #pragma unroll
  for (int mf = 0; mf < 8; ++mf)
    #pragma unroll
    for (int r = 0; r < 4; ++r){
      float p = tanh_fast(acc2[mf][0][r] + ba1v[0]) * wa2v[0]
              + tanh_fast(acc2[mf][1][r] + ba1v[1]) * wa2v[1];
      p += __shfl_xor(p, 1);
      p += __shfl_xor(p, 2);
      p += __shfl_xor(p, 4);
      p += __shfl_xor(p, 8);
      if (l15 == 0){
        int row = mf*16 + l4*4 + r;
        sc4[row*4 + wid] = p;
      }
    }
  __syncthreads();

  if (tid < 128){
    float s = sc4[tid*4+0] + sc4[tid*4+1] + sc4[tid*4+2] + sc4[tid*4+3] + ba2v[0];
    evec[tid] = __expf(s);   // |s| <= ~2.2 (tanh-bounded) — no max-subtraction
  }
  __syncthreads();

  // -------- weighted partial reduce: P[f] = sum_r e[r]*h[r][f] --------
  {
    const int f0 = (tid & 127) << 1;
    const int g  = tid >> 7;           // 2 row groups of 64
    float p0 = 0.f, p1 = 0.f;
    const int rbase = g << 6;
    #pragma unroll 8
    for (int i = 0; i < 64; ++i){
      const int r = rbase + i;
      const uint32_t hw = *(const uint32_t*)(HsB + ((r*512 + f0*2) ^ SWZH(r)));
      const float e = evec[r];
      p0 = fmaf(e, bf2f((unsigned short)(hw & 0xffffu)), p0);
      p1 = fmaf(e, bf2f((unsigned short)(hw >> 16)),     p1);
    }
    Pp[(g << 8) + f0]     = p0;
    Pp[(g << 8) + f0 + 1] = p1;
  }
  __syncthreads();

  const int bag = bRow >> 13;   // 8192 rows per bag
  {
    float s = Pp[tid] + Pp[256 + tid];
    atomicAdd(&bagAcc[bag*257 + tid], s);
  }
  if (tid < 64){
    float se = evec[tid] + evec[tid + 64];
    se += __shfl_xor(se, 1);
    se += __shfl_xor(se, 2);
    se += __shfl_xor(se, 4);
    se += __shfl_xor(se, 8);
    se += __shfl_xor(se, 16);
    se += __shfl_xor(se, 32);
    if (tid == 0) atomicAdd(&bagAcc[bag*257 + 256], se);
  }
}

// ---------- head: out[b,d] = (P[b]/E[b]) . Wh[d] + bh[d] ----------
__global__ void head_kernel(const float* __restrict__ bagAcc,
                            const float* __restrict__ wh,
                            const float* __restrict__ bh,
                            float* __restrict__ out){
  int t = threadIdx.x;          // 64 threads: b = t>>1, d = t&1
  int b = t >> 1, d = t & 1;
  const float* P = bagAcc + b*257;
  float invE = 1.f / P[256];
  float acc = 0.f;
  for (int f = 0; f < 256; ++f) acc += P[f] * wh[d*256 + f];
  out[b*2 + d] = acc * invE + bh[d];
}

extern "C" void kernel_launch(void* const* d_in, const int* in_sizes, int n_in,
                              void* d_out, int out_size, void* d_ws, size_t ws_size,
                              hipStream_t stream){
  const float* feat = (const float*)d_in[0];
  const float* W1   = (const float*)d_in[1];
  const float* b1   = (const float*)d_in[2];
  const float* Wa1  = (const float*)d_in[3];
  const float* ba1  = (const float*)d_in[4];
  const float* Wa2  = (const float*)d_in[5];
  const float* ba2  = (const float*)d_in[6];
  const float* Wh   = (const float*)d_in[7];
  const float* bh   = (const float*)d_in[8];
  // d_in[9]: bag_sizes — uniform 8192 (N_PATCHES/N_BAGS), bags contiguous.

  unsigned short* w1b  = (unsigned short*)d_ws;                        // 512 KB
  unsigned short* wa1b = (unsigned short*)((char*)d_ws + 524288);      // 64 KB
  float* bagAcc        = (float*)((char*)d_ws + 589824);               // 32*257 f32

  prep_kernel<<<1185, 256, 0, stream>>>(W1, Wa1, w1b, wa1b, bagAcc);

  mil_main<<<NBLK, 256, 70144, stream>>>(feat, w1b, b1, wa1b, ba1,
                                         Wa2, ba2, bagAcc);

  head_kernel<<<1, 64, 0, stream>>>(bagAcc, Wh, bh, (float*)d_out);
}